// Round 18
// baseline (136.628 us; speedup 1.0000x reference)
//
#include <hip/hip_runtime.h>

#define NUM_EMBED 1024
#define EMBED_DIM 256
#define SPATIAL 4096          // 64*64
#define NROWS 65536           // 16*4096
#define EMBED_ELEMS 16777216  // 16*256*4096
#define HMARGIN 0.05f         // margin on h = d2/2 scores (== 0.1 on d2)

typedef _Float16 half8 __attribute__((ext_vector_type(8)));
typedef float f32x4 __attribute__((ext_vector_type(4)));

__device__ __forceinline__ unsigned fkey(float f) {
  unsigned u = __float_as_uint(f);
  return (u & 0x80000000u) ? ~u : (u | 0x80000000u);
}

#define UPD(V1, V2, I1, S, I)                            \
  { float _s = (S);                                      \
    if (_s < (V1)) { (V2) = (V1); (V1) = _s; (I1) = (I); } \
    else if (_s < (V2)) { (V2) = _s; } }

#define MERGE(V1A, V2A, I1A, V1B, V2B, I1B)                       \
  { if ((V1B) < (V1A)) { (V2A) = fminf((V1A), (V2B)); (V1A) = (V1B); (I1A) = (I1B); } \
    else { (V2A) = fminf((V2A), (V1B)); } }

// ---------------- init: used, flagcount, cnorm, cb16 (PERMUTED, 16-code chunks) ----------------
// cb16p[ch*4096 + ks*512 + lane*8 + q] = cb[(ch*16 + (lane&15))*256 + ks*32 + (lane>>4)*8 + q]
__global__ __launch_bounds__(256) void k_init(const float* __restrict__ cb,
                                              int* __restrict__ used,
                                              int* __restrict__ flagcount,
                                              float* __restrict__ cnorm,
                                              _Float16* __restrict__ cb16) {
  int bid = blockIdx.x, tid = threadIdx.x;
  if (bid == 0) {
    used[tid] = 0; used[tid + 256] = 0; used[tid + 512] = 0; used[tid + 768] = 0;
    if (tid == 0) *flagcount = 0;
  } else if (bid <= 64) {
    int c = (bid - 1) * 16 + (tid >> 4);
    int l = tid & 15;
    const float4* p = (const float4*)(cb + c * EMBED_DIM + l * 16);
    float s = 0.f;
#pragma unroll
    for (int j = 0; j < 4; ++j) {
      float4 v = p[j];
      s += v.x * v.x + v.y * v.y + v.z * v.z + v.w * v.w;
    }
#pragma unroll
    for (int off = 1; off < 16; off <<= 1) s += __shfl_xor(s, off, 16);
    if (l == 0) cnorm[c] = s;
  } else {
    int gid = (bid - 65) * 256 + tid;  // 0..32767
    int ch = gid >> 9;                 // 64 chunks of 16 codes
    int rem = gid & 511;
    int ks = rem >> 6;
    int lg = (rem >> 4) & 3;
    int ln = rem & 15;
    int S = (ch * 16 + ln) * 256 + ks * 32 + lg * 8;
    const float4* src = (const float4*)(cb + S);
    float4 a = src[0], b = src[1];
    half8 h;
    h[0] = (_Float16)a.x; h[1] = (_Float16)a.y; h[2] = (_Float16)a.z; h[3] = (_Float16)a.w;
    h[4] = (_Float16)b.x; h[5] = (_Float16)b.y; h[6] = (_Float16)b.z; h[7] = (_Float16)b.w;
    *(half8*)(cb16 + gid * 8) = h;
  }
}

// ---------------- fp16 MFMA screening: 2-DEEP reg lookahead + double LDS buffer ----------------
// R17 data path; staging deepened: named stg sets sa/sb (static, rule #20),
// per-wave buffers B0/B1 (16 KB/wave). Compiler's reg-dep waits become counted
// vmcnt(8) — one load set always in flight; waves' load bursts desynchronize.
__global__ __launch_bounds__(256, 2) void k_score(const float* __restrict__ in,
                                                  const _Float16* __restrict__ cb16,
                                                  const float* __restrict__ cnorm,
                                                  float* __restrict__ out_idx,
                                                  int* __restrict__ idxi,
                                                  int* __restrict__ flagged,
                                                  int* __restrict__ flagcount,
                                                  int* __restrict__ used,
                                                  double* __restrict__ partials) {
  __shared__ _Float16 As[8][4096];  // 64 KB: wave w owns 16 KB (B0,B1); also X scratch
  __shared__ float cn_lds[1024];    // 4 KB, pre-scaled x0.5
  int tid = threadIdx.x;
  int lane = tid & 63;
  int wave = tid >> 6;
  int ln = lane & 15;
  int lg = lane >> 4;
  int r0 = blockIdx.x << 6;  // 64 rows/block
  const float* Ain = in + ((r0 >> 12) * (EMBED_DIM * SPATIAL)) + (r0 & 4095);

  // ---- block-wide X transpose into first 32 KB: [kc 0..31][row 0..63] 16B ----
  {
    char* scratch = (char*)As[0];
    int row = tid & 63;
    int kq = tid >> 6;
    const float* p0 = Ain + row;
#pragma unroll
    for (int j = 0; j < 8; ++j) {
      int kc = kq * 8 + j;
      half8 hv;
#pragma unroll
      for (int q = 0; q < 8; ++q) hv[q] = (_Float16)p0[(kc * 8 + q) * SPATIAL];
      *(half8*)(scratch + kc * 1024 + row * 16) = hv;
    }
#pragma unroll
    for (int i = 0; i < 4; ++i) cn_lds[tid + 256 * i] = 0.5f * cnorm[tid + 256 * i];
  }
  __syncthreads();
  half8 xf[8][4];  // all 64 rows x K=256
  {
    const char* scratch = (const char*)As[0];
#pragma unroll
    for (int ks = 0; ks < 8; ++ks)
#pragma unroll
      for (int nf = 0; nf < 4; ++nf)
        xf[ks][nf] = *(const half8*)(scratch + (ks * 4 + lg) * 1024 + (nf * 16 + ln) * 16);
  }
  __syncthreads();  // scratch free for the per-wave buffers

  // per-wave double buffer + permuted source base (wave w -> chunks 16w..16w+15)
  char* B0 = (char*)As[0] + wave * 16384;
  char* B1 = B0 + 8192;
  const _Float16* src0 = cb16 + wave * 65536 + lane * 8;

  float sv1[4] = {3e38f, 3e38f, 3e38f, 3e38f};
  float sv2[4] = {3e38f, 3e38f, 3e38f, 3e38f};
  int si1[4] = {0, 0, 0, 0};
  int afo = lg * 256 + ln * 16;

  // prologue: SA<-0, SB<-1, write B0(0), SA<-2
  half8 sa[8], sb[8];
#pragma unroll
  for (int i = 0; i < 8; ++i) sa[i] = *(const half8*)(src0 + i * 512);
#pragma unroll
  for (int i = 0; i < 8; ++i) sb[i] = *(const half8*)(src0 + 4096 + i * 512);
#pragma unroll
  for (int i = 0; i < 8; ++i) *(half8*)(B0 + i * 1024 + lane * 16) = sa[i];
#pragma unroll
  for (int i = 0; i < 8; ++i) sa[i] = *(const half8*)(src0 + 2 * 4096 + i * 512);

#define COMPUTE_FOLD(P, C)                                                          \
  {                                                                                 \
    f32x4 acc[4] = {};                                                              \
    __builtin_amdgcn_s_setprio(1);                                                  \
    _Pragma("unroll") for (int ks = 0; ks < 8; ++ks) {                              \
      half8 af = *(const half8*)((P) + ks * 1024 + afo);                            \
      _Pragma("unroll") for (int nf = 0; nf < 4; ++nf)                              \
          acc[nf] = __builtin_amdgcn_mfma_f32_16x16x32_f16(af, xf[ks][nf], acc[nf], \
                                                           0, 0, 0);                \
    }                                                                               \
    __builtin_amdgcn_s_setprio(0);                                                  \
    int cb0 = wave * 256 + (C)*16;                                                  \
    float cna[4];                                                                   \
    *(float4*)cna = *(const float4*)(cn_lds + cb0 + lg * 4);                        \
    int ib0 = cb0 + lg * 4;                                                         \
    _Pragma("unroll") for (int nf = 0; nf < 4; ++nf) {                              \
      float v1a = cna[0] - acc[nf][0], v2a = 3e38f;                                 \
      int i1a = ib0;                                                                \
      _Pragma("unroll") for (int r = 1; r < 4; ++r)                                 \
          UPD(v1a, v2a, i1a, cna[r] - acc[nf][r], ib0 + r);                         \
      MERGE(sv1[nf], sv2[nf], si1[nf], v1a, v2a, i1a);                              \
    }                                                                               \
  }

#pragma unroll 1
  for (int j = 0; j < 8; ++j) {
    int c0 = 2 * j;
    // write SB (chunk 2j+1) -> B1 (counted wait: only SB's loads)
#pragma unroll
    for (int i = 0; i < 8; ++i) *(half8*)(B1 + i * 1024 + lane * 16) = sb[i];
    if (j < 7) {
      const _Float16* ps = src0 + (2 * j + 3) * 4096;
#pragma unroll
      for (int i = 0; i < 8; ++i) sb[i] = *(const half8*)(ps + i * 512);
    }
    COMPUTE_FOLD(B0, c0);
    if (j < 7) {
      // write SA (chunk 2j+2) -> B0 (counted wait: only SA's loads)
#pragma unroll
      for (int i = 0; i < 8; ++i) *(half8*)(B0 + i * 1024 + lane * 16) = sa[i];
    }
    if (j < 6) {
      const _Float16* ps = src0 + (2 * j + 4) * 4096;
#pragma unroll
      for (int i = 0; i < 8; ++i) sa[i] = *(const half8*)(ps + i * 512);
    }
    COMPUTE_FOLD(B1, c0 + 1);
  }
#undef COMPUTE_FOLD

  // ---- epilogue Sum(x^2): wave 0's xf covers the block's 64x256 tile once ----
  float sx = 0.f;
  if (wave == 0) {
#pragma unroll
    for (int ks = 0; ks < 8; ++ks)
#pragma unroll
      for (int nf = 0; nf < 4; ++nf)
#pragma unroll
        for (int q = 0; q < 8; ++q) {
          float v = (float)xf[ks][nf][q];
          sx += v * v;
        }
#pragma unroll
    for (int off = 1; off < 64; off <<= 1) sx += __shfl_xor(sx, off, 64);
  }

  // ---- merge the 4 lane-groups (same rows, disjoint codes within the wave) ----
#pragma unroll
  for (int nf = 0; nf < 4; ++nf) {
#pragma unroll
    for (int off = 16; off < 64; off <<= 1) {
      float ov1 = __shfl_xor(sv1[nf], off);
      float ov2 = __shfl_xor(sv2[nf], off);
      int oi = __shfl_xor(si1[nf], off);
      if (ov1 < sv1[nf]) { sv2[nf] = fminf(sv1[nf], ov2); sv1[nf] = ov1; si1[nf] = oi; }
      else { sv2[nf] = fminf(sv2[nf], ov1); }
    }
  }

  // ---- cross-wave merge: waves hold disjoint code quarters of the SAME rows ----
  __syncthreads();  // all waves done with buffers
  float* mv1 = (float*)As[0];  // 256 f
  float* mv2 = mv1 + 256;
  int* mi1 = (int*)(mv2 + 256);
  if (lg == 0) {
#pragma unroll
    for (int nf = 0; nf < 4; ++nf) {
      int slot = wave * 64 + nf * 16 + ln;
      mv1[slot] = sv1[nf]; mv2[slot] = sv2[nf]; mi1[slot] = si1[nf];
    }
  }
  __syncthreads();
  if (tid < 64) {
    float v1 = mv1[tid], v2 = mv2[tid];
    int i1 = mi1[tid];
#pragma unroll
    for (int w = 1; w < 4; ++w)  // ascending code ranges: ties keep lowest
      MERGE(v1, v2, i1, mv1[w * 64 + tid], mv2[w * 64 + tid], mi1[w * 64 + tid]);
    int grow = r0 + tid;
    out_idx[grow] = (float)i1;
    idxi[grow] = i1;
    if (v2 - v1 < HMARGIN) {
      int p = atomicAdd(flagcount, 1);
      flagged[p] = grow;
    } else {
      used[i1] = 1;  // final winner for unflagged rows (ties always flagged)
    }
    // per-block loss partial: Sum(x^2) + 2*Sum(h_min)  (tid<64 == wave 0)
    float hsum = v1;
#pragma unroll
    for (int off = 1; off < 64; off <<= 1) hsum += __shfl_xor(hsum, off, 64);
    if (tid == 0)
      partials[blockIdx.x] = (double)sx + 2.0 * (double)hsum;
  }
}

// ---------------- exact fp32 re-rank: 1 row/block, 16-lane-per-code groups ----------------
__global__ __launch_bounds__(256) void k_cleanup(const float* __restrict__ in,
                                                 const float* __restrict__ cb,
                                                 const float* __restrict__ cnorm,
                                                 const int* __restrict__ flagged,
                                                 const int* __restrict__ flagcount,
                                                 float* __restrict__ out_idx,
                                                 int* __restrict__ idxi,
                                                 int* __restrict__ used) {
  __shared__ float xs[256];
  __shared__ unsigned long long red[4];
  int tid = threadIdx.x;
  int lane = tid & 63;
  int wave = tid >> 6;
  int sub = lane & 15;
  int cg = lane >> 4;
  int nf = *flagcount;
  const float4* cb4 = (const float4*)cb;
  for (int fi = blockIdx.x; fi < nf; fi += 2048) {
    int row = flagged[fi];
    int b = row >> 12, s = row & 4095;
    xs[tid] = in[b * (EMBED_DIM * SPATIAL) + tid * SPATIAL + s];
    __syncthreads();
    const float4* xs4 = (const float4*)xs;
    float4 x0 = xs4[sub], x1 = xs4[16 + sub], x2 = xs4[32 + sub], x3 = xs4[48 + sub];
    unsigned long long best = ~0ull;
    int c0 = wave * 256 + cg;
#pragma unroll 4
    for (int g = 0; g < 64; ++g) {
      int c = c0 + g * 4;
      const float4* crow = cb4 + c * 64 + sub;
      float4 d0 = crow[0], d1 = crow[16], d2 = crow[32], d3 = crow[48];
      float p = d0.x * x0.x + d0.y * x0.y + d0.z * x0.z + d0.w * x0.w;
      p += d1.x * x1.x + d1.y * x1.y + d1.z * x1.z + d1.w * x1.w;
      p += d2.x * x2.x + d2.y * x2.y + d2.z * x2.z + d2.w * x2.w;
      p += d3.x * x3.x + d3.y * x3.y + d3.z * x3.z + d3.w * x3.w;
#pragma unroll
      for (int off = 1; off < 16; off <<= 1) p += __shfl_xor(p, off);
      if (sub == 0) {
        float sc = cnorm[c] - 2.0f * p;
        unsigned long long k = ((unsigned long long)fkey(sc) << 32) | (unsigned)c;
        best = k < best ? k : best;
      }
    }
    {
      unsigned long long o = __shfl_xor(best, 16); best = o < best ? o : best;
      o = __shfl_xor(best, 32); best = o < best ? o : best;
    }
    if (lane == 0) red[wave] = best;
    __syncthreads();
    if (tid == 0) {
      unsigned long long bb = red[0];
#pragma unroll
      for (int w = 1; w < 4; ++w) { unsigned long long o = red[w]; bb = o < bb ? o : bb; }
      int idx = (int)(bb & 0xffffffffull);
      out_idx[row] = (float)idx;
      idxi[row] = idx;
      used[idx] = 1;
    }
    __syncthreads();
  }
}

// ---------------- gather embed (write-only; MSE fused into k_score) ----------------
__global__ __launch_bounds__(256) void k_gather(const float* __restrict__ cb,
                                                const int* __restrict__ idxi,
                                                float* __restrict__ embed_out) {
  __shared__ float E[32][257];  // ~33 KB
  __shared__ int idx_l[32];
  int tid = threadIdx.x;
  int lane = tid & 63;
  int wave = tid >> 6;
  int r0 = blockIdx.x << 5;  // 32 spatial positions (same batch)
  int b = r0 >> 12;
  int s0 = r0 & 4095;
  if (tid < 32) idx_l[tid] = idxi[r0 + tid];
  __syncthreads();
  const float4* cb4 = (const float4*)cb;
#pragma unroll
  for (int jj = 0; jj < 8; ++jj) {
    int j = wave * 8 + jj;
    float4 v = cb4[idx_l[j] * 64 + lane];
    E[j][lane * 4 + 0] = v.x;
    E[j][lane * 4 + 1] = v.y;
    E[j][lane * 4 + 2] = v.z;
    E[j][lane * 4 + 3] = v.w;
  }
  __syncthreads();
  int s = lane & 31;
  int dpar = lane >> 5;  // wave covers 2 d per instruction
  float* outp = embed_out + b * (EMBED_DIM * SPATIAL) + s0 + s;
#pragma unroll 8
  for (int i = 0; i < 32; ++i) {
    int d = wave * 64 + i * 2 + dpar;
    outp[d * SPATIAL] = E[s][d];
  }
}

// ---------------- tail: loss scalar + new_last_used ----------------
__global__ __launch_bounds__(256) void k_tail(const double* __restrict__ partials,
                                              const int* __restrict__ used,
                                              const int* __restrict__ last_used,
                                              float* __restrict__ out_loss,
                                              float* __restrict__ out_lu) {
  int tid = threadIdx.x;
  double s = 0.0;
  for (int i = tid; i < 1024; i += 256) s += partials[i];
#pragma unroll
  for (int off = 1; off < 64; off <<= 1) s += __shfl_xor(s, off, 64);
  __shared__ double sd[4];
  if ((tid & 63) == 0) sd[tid >> 6] = s;
  __syncthreads();
  if (tid == 0) {
    double total = sd[0] + sd[1] + sd[2] + sd[3];
    out_loss[0] = (float)(1.25 * total / (double)EMBED_ELEMS);
  }
  for (int i = tid; i < NUM_EMBED; i += 256)
    out_lu[i] = used[i] ? 0.0f : (float)(last_used[i] + 1);
}

extern "C" void kernel_launch(void* const* d_in, const int* in_sizes, int n_in,
                              void* d_out, int out_size, void* d_ws, size_t ws_size,
                              hipStream_t stream) {
  const float* in = (const float*)d_in[0];
  const float* cb = (const float*)d_in[1];
  const int* last_used = (const int*)d_in[2];

  float* out = (float*)d_out;
  float* out_idx = out;                       // 65536
  float* embed_out = out + NROWS;             // 16777216
  float* out_loss = embed_out + EMBED_ELEMS;  // 1
  float* out_lu = out_loss + 1;               // 1024

  _Float16* cb16 = (_Float16*)d_ws;                            // 512 KB (permuted)
  double* partials = (double*)(cb16 + NUM_EMBED * EMBED_DIM);  // 1024 double (+pad)
  int* flagged = (int*)(partials + 4096);                      // 65536 int
  int* flagcount = flagged + NROWS;                            // 16 int
  int* idxi = flagcount + 16;                                  // 65536 int
  int* used = idxi + NROWS;                                    // 1024 int
  float* cnorm = (float*)(used + NUM_EMBED);                   // 1024 float

  hipLaunchKernelGGL(k_init, dim3(193), dim3(256), 0, stream, cb, used, flagcount, cnorm, cb16);
  hipLaunchKernelGGL(k_score, dim3(1024), dim3(256), 0, stream, in, cb16, cnorm, out_idx,
                     idxi, flagged, flagcount, used, partials);
  hipLaunchKernelGGL(k_cleanup, dim3(2048), dim3(256), 0, stream, in, cb, cnorm, flagged,
                     flagcount, out_idx, idxi, used);
  hipLaunchKernelGGL(k_gather, dim3(2048), dim3(256), 0, stream, cb, idxi, embed_out);
  hipLaunchKernelGGL(k_tail, dim3(1), dim3(256), 0, stream, partials, used, last_used,
                     out_loss, out_lu);
}

// Round 19
// 120.527 us; speedup vs baseline: 1.1336x; 1.1336x over previous
//
#include <hip/hip_runtime.h>

#define NUM_EMBED 1024
#define EMBED_DIM 256
#define SPATIAL 4096          // 64*64
#define NROWS 65536           // 16*4096
#define EMBED_ELEMS 16777216  // 16*256*4096
#define HMARGIN 0.05f         // margin on h = d2/2 scores (== 0.1 on d2)

typedef _Float16 half8 __attribute__((ext_vector_type(8)));
typedef float f32x4 __attribute__((ext_vector_type(4)));

__device__ __forceinline__ unsigned fkey(float f) {
  unsigned u = __float_as_uint(f);
  return (u & 0x80000000u) ? ~u : (u | 0x80000000u);
}

#define UPD(V1, V2, I1, S, I)                            \
  { float _s = (S);                                      \
    if (_s < (V1)) { (V2) = (V1); (V1) = _s; (I1) = (I); } \
    else if (_s < (V2)) { (V2) = _s; } }

#define MERGE(V1A, V2A, I1A, V1B, V2B, I1B)                       \
  { if ((V1B) < (V1A)) { (V2A) = fminf((V1A), (V2B)); (V1A) = (V1B); (I1A) = (I1B); } \
    else { (V2A) = fminf((V2A), (V1B)); } }

// ---------------- init: used, flagcount, cnorm, cb16 (PERMUTED, 16-code chunks) ----------------
// cb16p[ch*4096 + ks*512 + lane*8 + q] = cb[(ch*16 + (lane&15))*256 + ks*32 + (lane>>4)*8 + q]
__global__ __launch_bounds__(256) void k_init(const float* __restrict__ cb,
                                              int* __restrict__ used,
                                              int* __restrict__ flagcount,
                                              float* __restrict__ cnorm,
                                              _Float16* __restrict__ cb16) {
  int bid = blockIdx.x, tid = threadIdx.x;
  if (bid == 0) {
    used[tid] = 0; used[tid + 256] = 0; used[tid + 512] = 0; used[tid + 768] = 0;
    if (tid == 0) *flagcount = 0;
  } else if (bid <= 64) {
    int c = (bid - 1) * 16 + (tid >> 4);
    int l = tid & 15;
    const float4* p = (const float4*)(cb + c * EMBED_DIM + l * 16);
    float s = 0.f;
#pragma unroll
    for (int j = 0; j < 4; ++j) {
      float4 v = p[j];
      s += v.x * v.x + v.y * v.y + v.z * v.z + v.w * v.w;
    }
#pragma unroll
    for (int off = 1; off < 16; off <<= 1) s += __shfl_xor(s, off, 16);
    if (l == 0) cnorm[c] = s;
  } else {
    int gid = (bid - 65) * 256 + tid;  // 0..32767
    int ch = gid >> 9;                 // 64 chunks of 16 codes
    int rem = gid & 511;
    int ks = rem >> 6;
    int lg = (rem >> 4) & 3;
    int ln = rem & 15;
    int S = (ch * 16 + ln) * 256 + ks * 32 + lg * 8;
    const float4* src = (const float4*)(cb + S);
    float4 a = src[0], b = src[1];
    half8 h;
    h[0] = (_Float16)a.x; h[1] = (_Float16)a.y; h[2] = (_Float16)a.z; h[3] = (_Float16)a.w;
    h[4] = (_Float16)b.x; h[5] = (_Float16)b.y; h[6] = (_Float16)b.z; h[7] = (_Float16)b.w;
    *(half8*)(cb16 + gid * 8) = h;
  }
}

// ---------------- fp16 MFMA screening + loss partial (R17 exact) ----------------
__global__ __launch_bounds__(256, 2) void k_score(const float* __restrict__ in,
                                                  const _Float16* __restrict__ cb16,
                                                  const float* __restrict__ cnorm,
                                                  float* __restrict__ out_idx,
                                                  int* __restrict__ idxi,
                                                  int* __restrict__ flagged,
                                                  int* __restrict__ flagcount,
                                                  int* __restrict__ used,
                                                  double* __restrict__ partials) {
  __shared__ _Float16 As[4][4096];  // 32 KB: wave w owns 8 KB; also X-transpose scratch
  __shared__ float cn_lds[1024];    // 4 KB, pre-scaled x0.5
  int tid = threadIdx.x;
  int lane = tid & 63;
  int wave = tid >> 6;
  int ln = lane & 15;
  int lg = lane >> 4;
  int r0 = blockIdx.x << 6;  // 64 rows/block
  const float* Ain = in + ((r0 >> 12) * (EMBED_DIM * SPATIAL)) + (r0 & 4095);

  // ---- block-wide X transpose into the 32 KB scratch: [kc 0..31][row 0..63] 16B ----
  {
    char* scratch = (char*)As[0];
    int row = tid & 63;
    int kq = tid >> 6;
    const float* p0 = Ain + row;
#pragma unroll
    for (int j = 0; j < 8; ++j) {
      int kc = kq * 8 + j;
      half8 hv;
#pragma unroll
      for (int q = 0; q < 8; ++q) hv[q] = (_Float16)p0[(kc * 8 + q) * SPATIAL];
      *(half8*)(scratch + kc * 1024 + row * 16) = hv;
    }
#pragma unroll
    for (int i = 0; i < 4; ++i) cn_lds[tid + 256 * i] = 0.5f * cnorm[tid + 256 * i];
  }
  __syncthreads();
  half8 xf[8][4];  // all 64 rows x K=256
  {
    const char* scratch = (const char*)As[0];
#pragma unroll
    for (int ks = 0; ks < 8; ++ks)
#pragma unroll
      for (int nf = 0; nf < 4; ++nf)
        xf[ks][nf] = *(const half8*)(scratch + (ks * 4 + lg) * 1024 + (nf * 16 + ln) * 16);
  }
  __syncthreads();  // scratch free for the per-wave buffers

  // wave-private 8 KB buffer + permuted source base (wave w -> chunks 16w..16w+15)
  char* buf = (char*)As[0] + wave * 8192;
  const _Float16* src0 = cb16 + wave * 65536 + lane * 8;

  // prologue: chunk 0 -> regs -> LDS
  half8 stg[8];
#pragma unroll
  for (int i = 0; i < 8; ++i) stg[i] = *(const half8*)(src0 + i * 512);
#pragma unroll
  for (int i = 0; i < 8; ++i) *(half8*)(buf + i * 1024 + lane * 16) = stg[i];

  float sv1[4] = {3e38f, 3e38f, 3e38f, 3e38f};
  float sv2[4] = {3e38f, 3e38f, 3e38f, 3e38f};
  int si1[4] = {0, 0, 0, 0};
  int afo = lg * 256 + ln * 16;

#pragma unroll 1
  for (int c = 0; c < 16; ++c) {
    // issue next chunk's loads EARLY (latency hides under this chunk's compute)
    if (c < 15) {
      const _Float16* ps = src0 + (c + 1) * 4096;
#pragma unroll
      for (int i = 0; i < 8; ++i) stg[i] = *(const half8*)(ps + i * 512);
    }
    // compute chunk c from the LDS buffer
    f32x4 acc[4] = {};
    __builtin_amdgcn_s_setprio(1);
#pragma unroll
    for (int ks = 0; ks < 8; ++ks) {
      half8 af = *(const half8*)(buf + ks * 1024 + afo);
#pragma unroll
      for (int nf = 0; nf < 4; ++nf)
        acc[nf] = __builtin_amdgcn_mfma_f32_16x16x32_f16(af, xf[ks][nf], acc[nf], 0, 0, 0);
    }
    __builtin_amdgcn_s_setprio(0);
    // fold: h = 0.5*|c|^2 - x.c ; codes cb0 + lg*4 + r, rows nf*16+ln
    int cb0 = wave * 256 + c * 16;
    float cna[4];
    *(float4*)cna = *(const float4*)(cn_lds + cb0 + lg * 4);
    int ib0 = cb0 + lg * 4;
#pragma unroll
    for (int nf = 0; nf < 4; ++nf) {
      float v1a = cna[0] - acc[nf][0], v2a = 3e38f;
      int i1a = ib0;
#pragma unroll
      for (int r = 1; r < 4; ++r) UPD(v1a, v2a, i1a, cna[r] - acc[nf][r], ib0 + r);
      MERGE(sv1[nf], sv2[nf], si1[nf], v1a, v2a, i1a);
    }
    // write next chunk into the buffer
    if (c < 15) {
#pragma unroll
      for (int i = 0; i < 8; ++i) *(half8*)(buf + i * 1024 + lane * 16) = stg[i];
    }
  }

  // ---- epilogue Sum(x^2): wave 0's xf covers the block's 64x256 tile once ----
  float sx = 0.f;
  if (wave == 0) {
#pragma unroll
    for (int ks = 0; ks < 8; ++ks)
#pragma unroll
      for (int nf = 0; nf < 4; ++nf)
#pragma unroll
        for (int q = 0; q < 8; ++q) {
          float v = (float)xf[ks][nf][q];
          sx += v * v;
        }
#pragma unroll
    for (int off = 1; off < 64; off <<= 1) sx += __shfl_xor(sx, off, 64);
  }

  // ---- merge the 4 lane-groups (same rows, disjoint codes within the wave) ----
#pragma unroll
  for (int nf = 0; nf < 4; ++nf) {
#pragma unroll
    for (int off = 16; off < 64; off <<= 1) {
      float ov1 = __shfl_xor(sv1[nf], off);
      float ov2 = __shfl_xor(sv2[nf], off);
      int oi = __shfl_xor(si1[nf], off);
      if (ov1 < sv1[nf]) { sv2[nf] = fminf(sv1[nf], ov2); sv1[nf] = ov1; si1[nf] = oi; }
      else { sv2[nf] = fminf(sv2[nf], ov1); }
    }
  }

  // ---- cross-wave merge: waves hold disjoint code quarters of the SAME rows ----
  __syncthreads();  // all waves done with buffers
  float* mv1 = (float*)As[0];  // 256 f
  float* mv2 = mv1 + 256;
  int* mi1 = (int*)(mv2 + 256);
  if (lg == 0) {
#pragma unroll
    for (int nf = 0; nf < 4; ++nf) {
      int slot = wave * 64 + nf * 16 + ln;
      mv1[slot] = sv1[nf]; mv2[slot] = sv2[nf]; mi1[slot] = si1[nf];
    }
  }
  __syncthreads();
  if (tid < 64) {
    float v1 = mv1[tid], v2 = mv2[tid];
    int i1 = mi1[tid];
#pragma unroll
    for (int w = 1; w < 4; ++w)  // ascending code ranges: ties keep lowest
      MERGE(v1, v2, i1, mv1[w * 64 + tid], mv2[w * 64 + tid], mi1[w * 64 + tid]);
    int grow = r0 + tid;
    out_idx[grow] = (float)i1;
    idxi[grow] = i1;
    if (v2 - v1 < HMARGIN) {
      int p = atomicAdd(flagcount, 1);
      flagged[p] = grow;
    } else {
      used[i1] = 1;  // final winner for unflagged rows (ties always flagged)
    }
    // per-block loss partial: Sum(x^2) + 2*Sum(h_min)  (tid<64 == wave 0)
    float hsum = v1;
#pragma unroll
    for (int off = 1; off < 64; off <<= 1) hsum += __shfl_xor(hsum, off, 64);
    if (tid == 0)
      partials[blockIdx.x] = (double)sx + 2.0 * (double)hsum;
  }
}

// ---------------- exact fp32 re-rank: 1 row/block, 16-lane-per-code groups ----------------
__global__ __launch_bounds__(256) void k_cleanup(const float* __restrict__ in,
                                                 const float* __restrict__ cb,
                                                 const float* __restrict__ cnorm,
                                                 const int* __restrict__ flagged,
                                                 const int* __restrict__ flagcount,
                                                 float* __restrict__ out_idx,
                                                 int* __restrict__ idxi,
                                                 int* __restrict__ used) {
  __shared__ float xs[256];
  __shared__ unsigned long long red[4];
  int tid = threadIdx.x;
  int lane = tid & 63;
  int wave = tid >> 6;
  int sub = lane & 15;
  int cg = lane >> 4;
  int nf = *flagcount;
  const float4* cb4 = (const float4*)cb;
  for (int fi = blockIdx.x; fi < nf; fi += 2048) {
    int row = flagged[fi];
    int b = row >> 12, s = row & 4095;
    xs[tid] = in[b * (EMBED_DIM * SPATIAL) + tid * SPATIAL + s];
    __syncthreads();
    const float4* xs4 = (const float4*)xs;
    float4 x0 = xs4[sub], x1 = xs4[16 + sub], x2 = xs4[32 + sub], x3 = xs4[48 + sub];
    unsigned long long best = ~0ull;
    int c0 = wave * 256 + cg;
#pragma unroll 4
    for (int g = 0; g < 64; ++g) {
      int c = c0 + g * 4;
      const float4* crow = cb4 + c * 64 + sub;
      float4 d0 = crow[0], d1 = crow[16], d2 = crow[32], d3 = crow[48];
      float p = d0.x * x0.x + d0.y * x0.y + d0.z * x0.z + d0.w * x0.w;
      p += d1.x * x1.x + d1.y * x1.y + d1.z * x1.z + d1.w * x1.w;
      p += d2.x * x2.x + d2.y * x2.y + d2.z * x2.z + d2.w * x2.w;
      p += d3.x * x3.x + d3.y * x3.y + d3.z * x3.z + d3.w * x3.w;
#pragma unroll
      for (int off = 1; off < 16; off <<= 1) p += __shfl_xor(p, off);
      if (sub == 0) {
        float sc = cnorm[c] - 2.0f * p;
        unsigned long long k = ((unsigned long long)fkey(sc) << 32) | (unsigned)c;
        best = k < best ? k : best;
      }
    }
    {
      unsigned long long o = __shfl_xor(best, 16); best = o < best ? o : best;
      o = __shfl_xor(best, 32); best = o < best ? o : best;
    }
    if (lane == 0) red[wave] = best;
    __syncthreads();
    if (tid == 0) {
      unsigned long long bb = red[0];
#pragma unroll
      for (int w = 1; w < 4; ++w) { unsigned long long o = red[w]; bb = o < bb ? o : bb; }
      int idx = (int)(bb & 0xffffffffull);
      out_idx[row] = (float)idx;
      idxi[row] = idx;
      used[idx] = 1;
    }
    __syncthreads();
  }
}

// ---------------- gather embed + fused tail (block 0 also does loss + last_used) ----------------
// Runs after k_cleanup: partials (k_score) and used (final) are complete.
__global__ __launch_bounds__(256) void k_gather(const float* __restrict__ cb,
                                                const int* __restrict__ idxi,
                                                float* __restrict__ embed_out,
                                                const double* __restrict__ partials,
                                                const int* __restrict__ used,
                                                const int* __restrict__ last_used,
                                                float* __restrict__ out_loss,
                                                float* __restrict__ out_lu) {
  __shared__ float E[32][257];  // ~33 KB
  __shared__ int idx_l[32];
  int tid = threadIdx.x;
  int lane = tid & 63;
  int wave = tid >> 6;
  int r0 = blockIdx.x << 5;  // 32 spatial positions (same batch)
  int b = r0 >> 12;
  int s0 = r0 & 4095;
  if (tid < 32) idx_l[tid] = idxi[r0 + tid];
  __syncthreads();
  const float4* cb4 = (const float4*)cb;
#pragma unroll
  for (int jj = 0; jj < 8; ++jj) {
    int j = wave * 8 + jj;
    float4 v = cb4[idx_l[j] * 64 + lane];
    E[j][lane * 4 + 0] = v.x;
    E[j][lane * 4 + 1] = v.y;
    E[j][lane * 4 + 2] = v.z;
    E[j][lane * 4 + 3] = v.w;
  }
  __syncthreads();
  int s = lane & 31;
  int dpar = lane >> 5;  // wave covers 2 d per instruction
  float* outp = embed_out + b * (EMBED_DIM * SPATIAL) + s0 + s;
#pragma unroll 8
  for (int i = 0; i < 32; ++i) {
    int d = wave * 64 + i * 2 + dpar;
    outp[d * SPATIAL] = E[s][d];
  }
  // ---- fused tail on block 0 ----
  if (blockIdx.x == 0) {
    double sum = 0.0;
    for (int i = tid; i < 1024; i += 256) sum += partials[i];
#pragma unroll
    for (int off = 1; off < 64; off <<= 1) sum += __shfl_xor(sum, off, 64);
    __shared__ double sd[4];
    if (lane == 0) sd[wave] = sum;
    __syncthreads();
    if (tid == 0) {
      double total = sd[0] + sd[1] + sd[2] + sd[3];
      out_loss[0] = (float)(1.25 * total / (double)EMBED_ELEMS);
    }
    for (int i = tid; i < NUM_EMBED; i += 256)
      out_lu[i] = used[i] ? 0.0f : (float)(last_used[i] + 1);
  }
}

extern "C" void kernel_launch(void* const* d_in, const int* in_sizes, int n_in,
                              void* d_out, int out_size, void* d_ws, size_t ws_size,
                              hipStream_t stream) {
  const float* in = (const float*)d_in[0];
  const float* cb = (const float*)d_in[1];
  const int* last_used = (const int*)d_in[2];

  float* out = (float*)d_out;
  float* out_idx = out;                       // 65536
  float* embed_out = out + NROWS;             // 16777216
  float* out_loss = embed_out + EMBED_ELEMS;  // 1
  float* out_lu = out_loss + 1;               // 1024

  _Float16* cb16 = (_Float16*)d_ws;                            // 512 KB (permuted)
  double* partials = (double*)(cb16 + NUM_EMBED * EMBED_DIM);  // 1024 double (+pad)
  int* flagged = (int*)(partials + 4096);                      // 65536 int
  int* flagcount = flagged + NROWS;                            // 16 int
  int* idxi = flagcount + 16;                                  // 65536 int
  int* used = idxi + NROWS;                                    // 1024 int
  float* cnorm = (float*)(used + NUM_EMBED);                   // 1024 float

  hipLaunchKernelGGL(k_init, dim3(193), dim3(256), 0, stream, cb, used, flagcount, cnorm, cb16);
  hipLaunchKernelGGL(k_score, dim3(1024), dim3(256), 0, stream, in, cb16, cnorm, out_idx,
                     idxi, flagged, flagcount, used, partials);
  hipLaunchKernelGGL(k_cleanup, dim3(2048), dim3(256), 0, stream, in, cb, cnorm, flagged,
                     flagcount, out_idx, idxi, used);
  hipLaunchKernelGGL(k_gather, dim3(2048), dim3(256), 0, stream, cb, idxi, embed_out,
                     partials, used, last_used, out_loss, out_lu);
}